// Round 16
// baseline (156.465 us; speedup 1.0000x reference)
//
#include <hip/hip_runtime.h>

#define N_NODES 50000
#define E_EDGES 600000
#define D_IN 128
#define O_OUT 128
#define R_REL 8
#define B_BAS 4
#define NB1 98                    // coarse buckets (512 dsts each)
#define NRT 3125                  // 50000 / 16 row tiles (exact)
#define NKC 20                    // 640 / 32 k-chunks
#define BKCAP 8192                // fixed per-bucket capacity (mean 6122, +26 sigma)
#define NRG 1563                  // ceil(50000/32) 32-row groups for gemm2

// fused prep+binA block ranges
#define NB_CONV 6250              // N*D/1024
#define NB_WT 320                 // 128*640/256
#define CHUNK_A 2048
#define NBA 293                   // ceil(600000/2048)

typedef __attribute__((ext_vector_type(8))) short bf16x8;
typedef __attribute__((ext_vector_type(4))) short bf16x4;
typedef __attribute__((ext_vector_type(4))) float f32x4;
typedef __attribute__((ext_vector_type(4))) unsigned short u16x4;

static __device__ __forceinline__ unsigned short f2bf(float f) {
    unsigned int u = __float_as_uint(f);
    unsigned int r = (u + 0x7fffu + ((u >> 16) & 1u)) >> 16;
    return (unsigned short)r;
}
static __device__ __forceinline__ float bf2f(unsigned short b) {
    return __uint_as_float(((unsigned int)b) << 16);
}

// Fused: x->bf16 convert | Wt2f fragment-layout weights | binA edge binning.
// (prep part and binA part touch disjoint data; cursor98 pre-zeroed by memset)
__global__ __launch_bounds__(256) void prepbin_kernel(const float* __restrict__ x,
                                                      unsigned short* __restrict__ xb,
                                                      const float* __restrict__ basis_v,
                                                      const float* __restrict__ w_loop,
                                                      unsigned short* __restrict__ Wt2f,
                                                      const int* __restrict__ src,
                                                      const int* __restrict__ dst,
                                                      const int* __restrict__ rel,
                                                      int* __restrict__ cursor98,
                                                      unsigned* __restrict__ coarse) {
    int b = blockIdx.x;
    if (b < NB_CONV) {
        int i = (b * 256 + threadIdx.x) * 4;
        float4 v = *(const float4*)&x[i];
        ushort4 o;
        o.x = f2bf(v.x); o.y = f2bf(v.y); o.z = f2bf(v.z); o.w = f2bf(v.w);
        *(ushort4*)&xb[i] = o;
    } else if (b < NB_CONV + NB_WT) {
        int i = (b - NB_CONV) * 256 + threadIdx.x;  // over 8*20*64*8 = 81920
        int j = i & 7, l = (i >> 3) & 63, rest = i >> 9;
        int kc = rest % NKC, ct = rest / NKC;
        int col = ct * 16 + (l & 15);
        int k = kc * 32 + (l >> 4) * 8 + j;
        int r = k >> 7, d = k & 127;
        float v = (r < B_BAS) ? basis_v[((size_t)r * D_IN + d) * O_OUT + col]
                              : w_loop[(size_t)d * O_OUT + col];
        Wt2f[i] = f2bf(v);
    } else {
        // binA: bin edges into 98 fixed-capacity coarse buckets
        __shared__ int hist[NB1];
        __shared__ int base[NB1];
        int t = threadIdx.x;
        if (t < NB1) hist[t] = 0;
        __syncthreads();
        int e0 = (b - NB_CONV - NB_WT) * CHUNK_A;
        for (int i = t; i < CHUNK_A; i += 256) {
            int e = e0 + i;
            if (e < E_EDGES) atomicAdd(&hist[dst[e] >> 9], 1);
        }
        __syncthreads();
        if (t < NB1) {
            int h = hist[t];
            base[t] = h ? atomicAdd(&cursor98[t], h) : 0;
            hist[t] = 0;
        }
        __syncthreads();
        for (int i = t; i < CHUNK_A; i += 256) {
            int e = e0 + i;
            if (e < E_EDGES) {
                int d = dst[e], bb = d >> 9;
                int pos = base[bb] + atomicAdd(&hist[bb], 1);
                coarse[(size_t)bb * BKCAP + pos] = (unsigned)src[e] | ((unsigned)rel[e] << 16)
                                                 | ((unsigned)(d & 511) << 19);
            }
        }
    }
}

// Pass B: one block per bucket. LDS (dst,rel) histogram -> invf + per-dst scan
// (begd/cntd) -> exact slot placement.
__global__ __launch_bounds__(512) void binB_kernel(const unsigned* __restrict__ coarse,
                                                   const int* __restrict__ cursor98,
                                                   unsigned* __restrict__ epack,
                                                   int* __restrict__ begd,
                                                   int* __restrict__ cntd,
                                                   float* __restrict__ invf) {
    __shared__ int hist[512 * 8];   // 16 KB: [dlow][rel]
    __shared__ int s[512];
    __shared__ int lcnt[512];
    int b = blockIdx.x, t = threadIdx.x;
    int d0 = b << 9, d = d0 + t;
    #pragma unroll
    for (int r = 0; r < 8; ++r) hist[t * 8 + r] = 0;
    __syncthreads();
    int cnt = cursor98[b];
    const unsigned* cb = coarse + (size_t)b * BKCAP;
    for (int i = t; i < cnt; i += 512) {
        unsigned p = cb[i];
        atomicAdd(&hist[((p >> 19) & 511) * 8 + ((p >> 16) & 7)], 1);
    }
    __syncthreads();
    int c = 0;
    if (d < N_NODES) {
        #pragma unroll
        for (int r = 0; r < 8; ++r) {
            int h = hist[t * 8 + r];
            c += h;
            invf[d * 8 + r] = 1.0f / (float)max(h, 1);
        }
    }
    s[t] = c;
    __syncthreads();
    #pragma unroll
    for (int off = 1; off < 512; off <<= 1) {
        int add = (t >= off) ? s[t - off] : 0;
        __syncthreads();
        s[t] += add;
        __syncthreads();
    }
    int ex = s[t] - c;
    if (d < N_NODES) {
        begd[d] = b * BKCAP + ex;
        cntd[d] = c;
    }
    lcnt[t] = ex;
    __syncthreads();
    for (int i = t; i < cnt; i += 512) {
        unsigned p = cb[i];
        int dlow = (p >> 19) & 511;
        int pos = atomicAdd(&lcnt[dlow], 1);
        epack[(size_t)b * BKCAP + pos] = p & 0x7ffffu;  // src | rel<<16
    }
}

// segagg: 32 lanes per dst node; 4-deep pipelined edge walk.
// yfrag stores are NON-TEMPORAL (written once, read once by gemm2) so the
// 12.8 MB xb gather table stays L2/L3-resident.
__global__ __launch_bounds__(256) void segagg_kernel(const unsigned short* __restrict__ xb,
                                                     const int* __restrict__ begd,
                                                     const int* __restrict__ cntd,
                                                     const float* __restrict__ invf,
                                                     const unsigned* __restrict__ epack,
                                                     const float* __restrict__ coeffs,
                                                     unsigned short* __restrict__ yfrag) {
    int d = blockIdx.x * 8 + (threadIdx.x >> 5);  // grid exact: 50000/8
    int l = threadIdx.x & 31;
    int beg = begd[d];
    int n = cntd[d];
    const unsigned* ep = epack + beg;
    float a0[4] = {}, a1[4] = {}, a2[4] = {}, a3[4] = {};
    int k = 0;
    for (; k + 4 <= n; k += 4) {
        unsigned p0 = ep[k], p1 = ep[k + 1], p2 = ep[k + 2], p3 = ep[k + 3];
        int s0 = p0 & 0xffffu, r0 = p0 >> 16;
        int s1 = p1 & 0xffffu, r1 = p1 >> 16;
        int s2 = p2 & 0xffffu, r2 = p2 >> 16;
        int s3 = p3 & 0xffffu, r3 = p3 >> 16;
        bf16x4 v0 = *(const bf16x4*)&xb[(size_t)s0 * D_IN + l * 4];
        bf16x4 v1 = *(const bf16x4*)&xb[(size_t)s1 * D_IN + l * 4];
        bf16x4 v2 = *(const bf16x4*)&xb[(size_t)s2 * D_IN + l * 4];
        bf16x4 v3 = *(const bf16x4*)&xb[(size_t)s3 * D_IN + l * 4];
        float i0 = invf[d * R_REL + r0];
        float i1 = invf[d * R_REL + r1];
        float i2 = invf[d * R_REL + r2];
        float i3 = invf[d * R_REL + r3];
        float4 cA = *(const float4*)&coeffs[r0 * B_BAS];
        float4 cB = *(const float4*)&coeffs[r1 * B_BAS];
        float4 cC = *(const float4*)&coeffs[r2 * B_BAS];
        float4 cD = *(const float4*)&coeffs[r3 * B_BAS];
        cA.x *= i0; cA.y *= i0; cA.z *= i0; cA.w *= i0;
        cB.x *= i1; cB.y *= i1; cB.z *= i1; cB.w *= i1;
        cC.x *= i2; cC.y *= i2; cC.z *= i2; cC.w *= i2;
        cD.x *= i3; cD.y *= i3; cD.z *= i3; cD.w *= i3;
        #pragma unroll
        for (int j = 0; j < 4; ++j) {
            float x0 = bf2f((unsigned short)v0[j]);
            float x1 = bf2f((unsigned short)v1[j]);
            float x2 = bf2f((unsigned short)v2[j]);
            float x3 = bf2f((unsigned short)v3[j]);
            a0[j] += cA.x * x0; a1[j] += cA.y * x0;
            a2[j] += cA.z * x0; a3[j] += cA.w * x0;
            a0[j] += cB.x * x1; a1[j] += cB.y * x1;
            a2[j] += cB.z * x1; a3[j] += cB.w * x1;
            a0[j] += cC.x * x2; a1[j] += cC.y * x2;
            a2[j] += cC.z * x2; a3[j] += cC.w * x2;
            a0[j] += cD.x * x3; a1[j] += cD.y * x3;
            a2[j] += cD.z * x3; a3[j] += cD.w * x3;
        }
    }
    for (; k < n; ++k) {
        unsigned p0 = ep[k];
        int s0 = p0 & 0xffffu, r0 = p0 >> 16;
        bf16x4 v0 = *(const bf16x4*)&xb[(size_t)s0 * D_IN + l * 4];
        float i0 = invf[d * R_REL + r0];
        float4 cA = *(const float4*)&coeffs[r0 * B_BAS];
        cA.x *= i0; cA.y *= i0; cA.z *= i0; cA.w *= i0;
        #pragma unroll
        for (int j = 0; j < 4; ++j) {
            float x0 = bf2f((unsigned short)v0[j]);
            a0[j] += cA.x * x0; a1[j] += cA.y * x0;
            a2[j] += cA.z * x0; a3[j] += cA.w * x0;
        }
    }
    // fragment-layout stores (non-temporal)
    int rt = d >> 4, lrow = d & 15;
    int kc0 = l >> 3, lhi = (l >> 1) & 3, jj = (l & 1) * 4;
    size_t rowbase = (size_t)rt * (NKC * 512);   // shorts per rt = 20*64*8
    #pragma unroll
    for (int b = 0; b < 4; ++b) {
        const float* ab = (b == 0) ? a0 : (b == 1) ? a1 : (b == 2) ? a2 : a3;
        u16x4 o;
        o.x = f2bf(ab[0]); o.y = f2bf(ab[1]); o.z = f2bf(ab[2]); o.w = f2bf(ab[3]);
        size_t addr = rowbase + ((size_t)(b * 4 + kc0) * 64 + lhi * 16 + lrow) * 8 + jj;
        __builtin_nontemporal_store(o, (u16x4*)&yfrag[addr]);
    }
    u16x4 xv = *(const u16x4*)&xb[(size_t)d * D_IN + l * 4];
    size_t addr = rowbase + ((size_t)(16 + kc0) * 64 + lhi * 16 + lrow) * 8 + jj;
    __builtin_nontemporal_store(xv, (u16x4*)&yfrag[addr]);
}

// gemm2: out = relu(A @ Wstack + bias), fragment-layout operands.
// Wave: 32 rows x 64 cols. yfrag loads and out stores are non-temporal;
// Wt2f (reused by all waves) stays cached.
__global__ __launch_bounds__(256) void gemm2_kernel(const unsigned short* __restrict__ yfrag,
                                                    const unsigned short* __restrict__ Wt2f,
                                                    const float* __restrict__ bias,
                                                    float* __restrict__ out) {
    const int w = threadIdx.x >> 6, l = threadIdx.x & 63;
    const int wid = blockIdx.x * 4 + w;
    if (wid >= NRG * 2) return;
    const int g = wid >> 1;
    const int ch = wid & 1;                    // col half: ct base 0 or 4
    const int rt0 = g * 2;
    const int rt1 = (rt0 + 1 < NRT) ? rt0 + 1 : rt0;   // clamp (last group)
    const bool has1 = (rt0 + 1 < NRT);
    const unsigned short* ya0 = yfrag + (size_t)rt0 * (NKC * 512) + l * 8;
    const unsigned short* ya1 = yfrag + (size_t)rt1 * (NKC * 512) + l * 8;
    const unsigned short* wb = Wt2f + (size_t)(ch * 4) * (NKC * 512) + l * 8;
    const int KSTEP = 512;

    f32x4 acc00 = {}, acc01 = {}, acc02 = {}, acc03 = {};
    f32x4 acc10 = {}, acc11 = {}, acc12 = {}, acc13 = {};

#define LA0(kc) __builtin_nontemporal_load((const bf16x8*)&ya0[(kc) * KSTEP])
#define LA1(kc) __builtin_nontemporal_load((const bf16x8*)&ya1[(kc) * KSTEP])
#define LB(ct, kc) (*(const bf16x8*)&wb[((ct) * NKC + (kc)) * KSTEP])

    bf16x8 aE0 = LA0(0), aE1 = LA1(0);
    bf16x8 bE0 = LB(0, 0), bE1 = LB(1, 0), bE2 = LB(2, 0), bE3 = LB(3, 0);
    bf16x8 aO0 = LA0(1), aO1 = LA1(1);
    bf16x8 bO0 = LB(0, 1), bO1 = LB(1, 1), bO2 = LB(2, 1), bO3 = LB(3, 1);

    #pragma unroll
    for (int kc = 0; kc < NKC; kc += 2) {
        acc00 = __builtin_amdgcn_mfma_f32_16x16x32_bf16(aE0, bE0, acc00, 0, 0, 0);
        acc01 = __builtin_amdgcn_mfma_f32_16x16x32_bf16(aE0, bE1, acc01, 0, 0, 0);
        acc02 = __builtin_amdgcn_mfma_f32_16x16x32_bf16(aE0, bE2, acc02, 0, 0, 0);
        acc03 = __builtin_amdgcn_mfma_f32_16x16x32_bf16(aE0, bE3, acc03, 0, 0, 0);
        acc10 = __builtin_amdgcn_mfma_f32_16x16x32_bf16(aE1, bE0, acc10, 0, 0, 0);
        acc11 = __builtin_amdgcn_mfma_f32_16x16x32_bf16(aE1, bE1, acc11, 0, 0, 0);
        acc12 = __builtin_amdgcn_mfma_f32_16x16x32_bf16(aE1, bE2, acc12, 0, 0, 0);
        acc13 = __builtin_amdgcn_mfma_f32_16x16x32_bf16(aE1, bE3, acc13, 0, 0, 0);
        if (kc + 2 < NKC) {
            aE0 = LA0(kc + 2); aE1 = LA1(kc + 2);
            bE0 = LB(0, kc + 2); bE1 = LB(1, kc + 2);
            bE2 = LB(2, kc + 2); bE3 = LB(3, kc + 2);
        }
        acc00 = __builtin_amdgcn_mfma_f32_16x16x32_bf16(aO0, bO0, acc00, 0, 0, 0);
        acc01 = __builtin_amdgcn_mfma_f32_16x16x32_bf16(aO0, bO1, acc01, 0, 0, 0);
        acc02 = __builtin_amdgcn_mfma_f32_16x16x32_bf16(aO0, bO2, acc02, 0, 0, 0);
        acc03 = __builtin_amdgcn_mfma_f32_16x16x32_bf16(aO0, bO3, acc03, 0, 0, 0);
        acc10 = __builtin_amdgcn_mfma_f32_16x16x32_bf16(aO1, bO0, acc10, 0, 0, 0);
        acc11 = __builtin_amdgcn_mfma_f32_16x16x32_bf16(aO1, bO1, acc11, 0, 0, 0);
        acc12 = __builtin_amdgcn_mfma_f32_16x16x32_bf16(aO1, bO2, acc12, 0, 0, 0);
        acc13 = __builtin_amdgcn_mfma_f32_16x16x32_bf16(aO1, bO3, acc13, 0, 0, 0);
        if (kc + 3 < NKC) {
            aO0 = LA0(kc + 3); aO1 = LA1(kc + 3);
            bO0 = LB(0, kc + 3); bO1 = LB(1, kc + 3);
            bO2 = LB(2, kc + 3); bO3 = LB(3, kc + 3);
        }
    }
#undef LA0
#undef LA1
#undef LB

    // epilogue: C/D layout col=lane&15, row=(lane>>4)*4+i  [m89-verified]
    const int lr = l & 15, lg = l >> 4;
    #pragma unroll
    for (int ct = 0; ct < 4; ++ct) {
        const f32x4& a0 = (ct == 0) ? acc00 : (ct == 1) ? acc01 : (ct == 2) ? acc02 : acc03;
        const f32x4& a1 = (ct == 0) ? acc10 : (ct == 1) ? acc11 : (ct == 2) ? acc12 : acc13;
        int col = (ch * 4 + ct) * 16 + lr;
        float bv = bias[col];
        #pragma unroll
        for (int i2 = 0; i2 < 4; ++i2) {
            int row0 = rt0 * 16 + lg * 4 + i2;
            __builtin_nontemporal_store(fmaxf(a0[i2] + bv, 0.f),
                                        &out[(size_t)row0 * O_OUT + col]);
        }
        if (has1) {
            #pragma unroll
            for (int i2 = 0; i2 < 4; ++i2) {
                int row1 = rt1 * 16 + lg * 4 + i2;
                __builtin_nontemporal_store(fmaxf(a1[i2] + bv, 0.f),
                                            &out[(size_t)row1 * O_OUT + col]);
            }
        }
    }
}

extern "C" void kernel_launch(void* const* d_in, const int* in_sizes, int n_in,
                              void* d_out, int out_size, void* d_ws, size_t ws_size,
                              hipStream_t stream) {
    (void)in_sizes; (void)n_in; (void)out_size; (void)ws_size;
    const float* x       = (const float*)d_in[0];
    const float* basis_v = (const float*)d_in[1];
    const float* coeffs  = (const float*)d_in[2];
    const float* w_loop  = (const float*)d_in[3];
    const float* bias_p  = (const float*)d_in[4];
    const int*   src     = (const int*)d_in[5];
    const int*   dst     = (const int*)d_in[6];
    const int*   rel     = (const int*)d_in[7];
    float* out = (float*)d_out;

    char* ws = (char*)d_ws;
    unsigned short* Wt2f     = (unsigned short*)(ws);             //     163,840 B
    unsigned short* xb       = (unsigned short*)(ws + 163840);    //  12,800,000 B
    float*          invf     = (float*)(ws + 12963840);           //   1,600,000 B
    int*            begd     = (int*)(ws + 14563840);             //     200,000 B
    int*            cntd     = (int*)(ws + 14763840);             //     200,000 B
    int*            cursor98 = (int*)(ws + 14963840);             //       1,024 B
    unsigned*       coarse   = (unsigned*)(ws + 14964864);        //   3,211,264 B
    unsigned*       epack    = (unsigned*)(ws + 18176128);        //   3,211,264 B
    unsigned short* yfrag    = (unsigned short*)(ws + 21387392);  //  64,000,000 B

    hipMemsetAsync(cursor98, 0, NB1 * sizeof(int), stream);
    prepbin_kernel<<<NB_CONV + NB_WT + NBA, 256, 0, stream>>>(x, xb, basis_v, w_loop, Wt2f,
                                                              src, dst, rel, cursor98, coarse);
    binB_kernel<<<NB1, 512, 0, stream>>>(coarse, cursor98, epack, begd, cntd, invf);
    segagg_kernel<<<N_NODES / 8, 256, 0, stream>>>(xb, begd, cntd, invf, epack, coeffs, yfrag);
    gemm2_kernel<<<(NRG * 2 + 3) / 4, 256, 0, stream>>>(yfrag, Wt2f, bias_p, out);
}

// Round 17
// 132.230 us; speedup vs baseline: 1.1833x; 1.1833x over previous
//
#include <hip/hip_runtime.h>

#define N_NODES 50000
#define E_EDGES 600000
#define D_IN 128
#define O_OUT 128
#define R_REL 8
#define B_BAS 4
#define NB1 98                    // coarse buckets (512 dsts each)
#define NRT 3125                  // 50000 / 16 row tiles (exact)
#define NKC 20                    // 640 / 32 k-chunks
#define BKCAP 8192                // fixed per-bucket capacity (mean 6122, +26 sigma)
#define NRG 1563                  // ceil(50000/32) 32-row groups for gemm2

// fused prep+binA block ranges
#define NB_CONV 6250              // N*D/1024
#define NB_WT 320                 // 128*640/256
#define CHUNK_A 2048
#define NBA 293                   // ceil(600000/2048)

typedef __attribute__((ext_vector_type(8))) short bf16x8;
typedef __attribute__((ext_vector_type(4))) short bf16x4;
typedef __attribute__((ext_vector_type(4))) float f32x4;

static __device__ __forceinline__ unsigned short f2bf(float f) {
    unsigned int u = __float_as_uint(f);
    unsigned int r = (u + 0x7fffu + ((u >> 16) & 1u)) >> 16;
    return (unsigned short)r;
}
static __device__ __forceinline__ float bf2f(unsigned short b) {
    return __uint_as_float(((unsigned int)b) << 16);
}

// Fused: x->bf16 convert | Wt2f fragment-layout weights | binA edge binning.
__global__ __launch_bounds__(256) void prepbin_kernel(const float* __restrict__ x,
                                                      unsigned short* __restrict__ xb,
                                                      const float* __restrict__ basis_v,
                                                      const float* __restrict__ w_loop,
                                                      unsigned short* __restrict__ Wt2f,
                                                      const int* __restrict__ src,
                                                      const int* __restrict__ dst,
                                                      const int* __restrict__ rel,
                                                      int* __restrict__ cursor98,
                                                      unsigned* __restrict__ coarse) {
    int b = blockIdx.x;
    if (b < NB_CONV) {
        int i = (b * 256 + threadIdx.x) * 4;
        float4 v = *(const float4*)&x[i];
        ushort4 o;
        o.x = f2bf(v.x); o.y = f2bf(v.y); o.z = f2bf(v.z); o.w = f2bf(v.w);
        *(ushort4*)&xb[i] = o;
    } else if (b < NB_CONV + NB_WT) {
        int i = (b - NB_CONV) * 256 + threadIdx.x;  // over 8*20*64*8 = 81920
        int j = i & 7, l = (i >> 3) & 63, rest = i >> 9;
        int kc = rest % NKC, ct = rest / NKC;
        int col = ct * 16 + (l & 15);
        int k = kc * 32 + (l >> 4) * 8 + j;
        int r = k >> 7, d = k & 127;
        float v = (r < B_BAS) ? basis_v[((size_t)r * D_IN + d) * O_OUT + col]
                              : w_loop[(size_t)d * O_OUT + col];
        Wt2f[i] = f2bf(v);
    } else {
        // binA: bin edges into 98 fixed-capacity coarse buckets
        __shared__ int hist[NB1];
        __shared__ int base[NB1];
        int t = threadIdx.x;
        if (t < NB1) hist[t] = 0;
        __syncthreads();
        int e0 = (b - NB_CONV - NB_WT) * CHUNK_A;
        for (int i = t; i < CHUNK_A; i += 256) {
            int e = e0 + i;
            if (e < E_EDGES) atomicAdd(&hist[dst[e] >> 9], 1);
        }
        __syncthreads();
        if (t < NB1) {
            int h = hist[t];
            base[t] = h ? atomicAdd(&cursor98[t], h) : 0;
            hist[t] = 0;
        }
        __syncthreads();
        for (int i = t; i < CHUNK_A; i += 256) {
            int e = e0 + i;
            if (e < E_EDGES) {
                int d = dst[e], bb = d >> 9;
                int pos = base[bb] + atomicAdd(&hist[bb], 1);
                coarse[(size_t)bb * BKCAP + pos] = (unsigned)src[e] | ((unsigned)rel[e] << 16)
                                                 | ((unsigned)(d & 511) << 19);
            }
        }
    }
}

// Pass B: one block per bucket. LDS (dst,rel) histogram -> invf + per-dst scan
// (begd/cntd) -> exact slot placement.
__global__ __launch_bounds__(512) void binB_kernel(const unsigned* __restrict__ coarse,
                                                   const int* __restrict__ cursor98,
                                                   unsigned* __restrict__ epack,
                                                   int* __restrict__ begd,
                                                   int* __restrict__ cntd,
                                                   float* __restrict__ invf) {
    __shared__ int hist[512 * 8];   // 16 KB: [dlow][rel]
    __shared__ int s[512];
    __shared__ int lcnt[512];
    int b = blockIdx.x, t = threadIdx.x;
    int d0 = b << 9, d = d0 + t;
    #pragma unroll
    for (int r = 0; r < 8; ++r) hist[t * 8 + r] = 0;
    __syncthreads();
    int cnt = cursor98[b];
    const unsigned* cb = coarse + (size_t)b * BKCAP;
    for (int i = t; i < cnt; i += 512) {
        unsigned p = cb[i];
        atomicAdd(&hist[((p >> 19) & 511) * 8 + ((p >> 16) & 7)], 1);
    }
    __syncthreads();
    int c = 0;
    if (d < N_NODES) {
        #pragma unroll
        for (int r = 0; r < 8; ++r) {
            int h = hist[t * 8 + r];
            c += h;
            invf[d * 8 + r] = 1.0f / (float)max(h, 1);
        }
    }
    s[t] = c;
    __syncthreads();
    #pragma unroll
    for (int off = 1; off < 512; off <<= 1) {
        int add = (t >= off) ? s[t - off] : 0;
        __syncthreads();
        s[t] += add;
        __syncthreads();
    }
    int ex = s[t] - c;
    if (d < N_NODES) {
        begd[d] = b * BKCAP + ex;
        cntd[d] = c;
    }
    lcnt[t] = ex;
    __syncthreads();
    for (int i = t; i < cnt; i += 512) {
        unsigned p = cb[i];
        int dlow = (p >> 19) & 511;
        int pos = atomicAdd(&lcnt[dlow], 1);
        epack[(size_t)b * BKCAP + pos] = p & 0x7ffffu;  // src | rel<<16
    }
}

// segagg: 32 lanes per dst node; 4-deep pipelined edge walk. REGULAR stores
// (scattered 8B writes rely on L2 line-merging; NT stores regressed, round 16).
__global__ __launch_bounds__(256) void segagg_kernel(const unsigned short* __restrict__ xb,
                                                     const int* __restrict__ begd,
                                                     const int* __restrict__ cntd,
                                                     const float* __restrict__ invf,
                                                     const unsigned* __restrict__ epack,
                                                     const float* __restrict__ coeffs,
                                                     unsigned short* __restrict__ yfrag) {
    int d = blockIdx.x * 8 + (threadIdx.x >> 5);  // grid exact: 50000/8
    int l = threadIdx.x & 31;
    int beg = begd[d];
    int n = cntd[d];
    const unsigned* ep = epack + beg;
    float a0[4] = {}, a1[4] = {}, a2[4] = {}, a3[4] = {};
    int k = 0;
    for (; k + 4 <= n; k += 4) {
        unsigned p0 = ep[k], p1 = ep[k + 1], p2 = ep[k + 2], p3 = ep[k + 3];
        int s0 = p0 & 0xffffu, r0 = p0 >> 16;
        int s1 = p1 & 0xffffu, r1 = p1 >> 16;
        int s2 = p2 & 0xffffu, r2 = p2 >> 16;
        int s3 = p3 & 0xffffu, r3 = p3 >> 16;
        bf16x4 v0 = *(const bf16x4*)&xb[(size_t)s0 * D_IN + l * 4];
        bf16x4 v1 = *(const bf16x4*)&xb[(size_t)s1 * D_IN + l * 4];
        bf16x4 v2 = *(const bf16x4*)&xb[(size_t)s2 * D_IN + l * 4];
        bf16x4 v3 = *(const bf16x4*)&xb[(size_t)s3 * D_IN + l * 4];
        float i0 = invf[d * R_REL + r0];
        float i1 = invf[d * R_REL + r1];
        float i2 = invf[d * R_REL + r2];
        float i3 = invf[d * R_REL + r3];
        float4 cA = *(const float4*)&coeffs[r0 * B_BAS];
        float4 cB = *(const float4*)&coeffs[r1 * B_BAS];
        float4 cC = *(const float4*)&coeffs[r2 * B_BAS];
        float4 cD = *(const float4*)&coeffs[r3 * B_BAS];
        cA.x *= i0; cA.y *= i0; cA.z *= i0; cA.w *= i0;
        cB.x *= i1; cB.y *= i1; cB.z *= i1; cB.w *= i1;
        cC.x *= i2; cC.y *= i2; cC.z *= i2; cC.w *= i2;
        cD.x *= i3; cD.y *= i3; cD.z *= i3; cD.w *= i3;
        #pragma unroll
        for (int j = 0; j < 4; ++j) {
            float x0 = bf2f((unsigned short)v0[j]);
            float x1 = bf2f((unsigned short)v1[j]);
            float x2 = bf2f((unsigned short)v2[j]);
            float x3 = bf2f((unsigned short)v3[j]);
            a0[j] += cA.x * x0; a1[j] += cA.y * x0;
            a2[j] += cA.z * x0; a3[j] += cA.w * x0;
            a0[j] += cB.x * x1; a1[j] += cB.y * x1;
            a2[j] += cB.z * x1; a3[j] += cB.w * x1;
            a0[j] += cC.x * x2; a1[j] += cC.y * x2;
            a2[j] += cC.z * x2; a3[j] += cC.w * x2;
            a0[j] += cD.x * x3; a1[j] += cD.y * x3;
            a2[j] += cD.z * x3; a3[j] += cD.w * x3;
        }
    }
    for (; k < n; ++k) {
        unsigned p0 = ep[k];
        int s0 = p0 & 0xffffu, r0 = p0 >> 16;
        bf16x4 v0 = *(const bf16x4*)&xb[(size_t)s0 * D_IN + l * 4];
        float i0 = invf[d * R_REL + r0];
        float4 cA = *(const float4*)&coeffs[r0 * B_BAS];
        cA.x *= i0; cA.y *= i0; cA.z *= i0; cA.w *= i0;
        #pragma unroll
        for (int j = 0; j < 4; ++j) {
            float x0 = bf2f((unsigned short)v0[j]);
            a0[j] += cA.x * x0; a1[j] += cA.y * x0;
            a2[j] += cA.z * x0; a3[j] += cA.w * x0;
        }
    }
    // fragment-layout stores
    int rt = d >> 4, lrow = d & 15;
    int kc0 = l >> 3, lhi = (l >> 1) & 3, jj = (l & 1) * 4;
    size_t rowbase = (size_t)rt * (NKC * 512);   // shorts per rt = 20*64*8
    #pragma unroll
    for (int b = 0; b < 4; ++b) {
        const float* ab = (b == 0) ? a0 : (b == 1) ? a1 : (b == 2) ? a2 : a3;
        ushort4 o;
        o.x = f2bf(ab[0]); o.y = f2bf(ab[1]); o.z = f2bf(ab[2]); o.w = f2bf(ab[3]);
        size_t addr = rowbase + ((size_t)(b * 4 + kc0) * 64 + lhi * 16 + lrow) * 8 + jj;
        *(ushort4*)&yfrag[addr] = o;
    }
    ushort4 xv = *(const ushort4*)&xb[(size_t)d * D_IN + l * 4];
    size_t addr = rowbase + ((size_t)(16 + kc0) * 64 + lhi * 16 + lrow) * 8 + jj;
    *(ushort4*)&yfrag[addr] = xv;
}

// gemm2: out = relu(A @ Wstack + bias), fragment-layout operands.
// Wave: 32 rows x 64 cols. NT yfrag loads + NT out stores (full-line streaming);
// Wt2f (reused by all waves) stays cached.
__global__ __launch_bounds__(256) void gemm2_kernel(const unsigned short* __restrict__ yfrag,
                                                    const unsigned short* __restrict__ Wt2f,
                                                    const float* __restrict__ bias,
                                                    float* __restrict__ out) {
    const int w = threadIdx.x >> 6, l = threadIdx.x & 63;
    const int wid = blockIdx.x * 4 + w;
    if (wid >= NRG * 2) return;
    const int g = wid >> 1;
    const int ch = wid & 1;                    // col half: ct base 0 or 4
    const int rt0 = g * 2;
    const int rt1 = (rt0 + 1 < NRT) ? rt0 + 1 : rt0;   // clamp (last group)
    const bool has1 = (rt0 + 1 < NRT);
    const unsigned short* ya0 = yfrag + (size_t)rt0 * (NKC * 512) + l * 8;
    const unsigned short* ya1 = yfrag + (size_t)rt1 * (NKC * 512) + l * 8;
    const unsigned short* wb = Wt2f + (size_t)(ch * 4) * (NKC * 512) + l * 8;
    const int KSTEP = 512;

    f32x4 acc00 = {}, acc01 = {}, acc02 = {}, acc03 = {};
    f32x4 acc10 = {}, acc11 = {}, acc12 = {}, acc13 = {};

#define LA0(kc) __builtin_nontemporal_load((const bf16x8*)&ya0[(kc) * KSTEP])
#define LA1(kc) __builtin_nontemporal_load((const bf16x8*)&ya1[(kc) * KSTEP])
#define LB(ct, kc) (*(const bf16x8*)&wb[((ct) * NKC + (kc)) * KSTEP])

    bf16x8 aE0 = LA0(0), aE1 = LA1(0);
    bf16x8 bE0 = LB(0, 0), bE1 = LB(1, 0), bE2 = LB(2, 0), bE3 = LB(3, 0);
    bf16x8 aO0 = LA0(1), aO1 = LA1(1);
    bf16x8 bO0 = LB(0, 1), bO1 = LB(1, 1), bO2 = LB(2, 1), bO3 = LB(3, 1);

    #pragma unroll
    for (int kc = 0; kc < NKC; kc += 2) {
        acc00 = __builtin_amdgcn_mfma_f32_16x16x32_bf16(aE0, bE0, acc00, 0, 0, 0);
        acc01 = __builtin_amdgcn_mfma_f32_16x16x32_bf16(aE0, bE1, acc01, 0, 0, 0);
        acc02 = __builtin_amdgcn_mfma_f32_16x16x32_bf16(aE0, bE2, acc02, 0, 0, 0);
        acc03 = __builtin_amdgcn_mfma_f32_16x16x32_bf16(aE0, bE3, acc03, 0, 0, 0);
        acc10 = __builtin_amdgcn_mfma_f32_16x16x32_bf16(aE1, bE0, acc10, 0, 0, 0);
        acc11 = __builtin_amdgcn_mfma_f32_16x16x32_bf16(aE1, bE1, acc11, 0, 0, 0);
        acc12 = __builtin_amdgcn_mfma_f32_16x16x32_bf16(aE1, bE2, acc12, 0, 0, 0);
        acc13 = __builtin_amdgcn_mfma_f32_16x16x32_bf16(aE1, bE3, acc13, 0, 0, 0);
        if (kc + 2 < NKC) {
            aE0 = LA0(kc + 2); aE1 = LA1(kc + 2);
            bE0 = LB(0, kc + 2); bE1 = LB(1, kc + 2);
            bE2 = LB(2, kc + 2); bE3 = LB(3, kc + 2);
        }
        acc00 = __builtin_amdgcn_mfma_f32_16x16x32_bf16(aO0, bO0, acc00, 0, 0, 0);
        acc01 = __builtin_amdgcn_mfma_f32_16x16x32_bf16(aO0, bO1, acc01, 0, 0, 0);
        acc02 = __builtin_amdgcn_mfma_f32_16x16x32_bf16(aO0, bO2, acc02, 0, 0, 0);
        acc03 = __builtin_amdgcn_mfma_f32_16x16x32_bf16(aO0, bO3, acc03, 0, 0, 0);
        acc10 = __builtin_amdgcn_mfma_f32_16x16x32_bf16(aO1, bO0, acc10, 0, 0, 0);
        acc11 = __builtin_amdgcn_mfma_f32_16x16x32_bf16(aO1, bO1, acc11, 0, 0, 0);
        acc12 = __builtin_amdgcn_mfma_f32_16x16x32_bf16(aO1, bO2, acc12, 0, 0, 0);
        acc13 = __builtin_amdgcn_mfma_f32_16x16x32_bf16(aO1, bO3, acc13, 0, 0, 0);
        if (kc + 3 < NKC) {
            aO0 = LA0(kc + 3); aO1 = LA1(kc + 3);
            bO0 = LB(0, kc + 3); bO1 = LB(1, kc + 3);
            bO2 = LB(2, kc + 3); bO3 = LB(3, kc + 3);
        }
    }
#undef LA0
#undef LA1
#undef LB

    // epilogue: C/D layout col=lane&15, row=(lane>>4)*4+i  [m89-verified]
    const int lr = l & 15, lg = l >> 4;
    #pragma unroll
    for (int ct = 0; ct < 4; ++ct) {
        const f32x4& a0 = (ct == 0) ? acc00 : (ct == 1) ? acc01 : (ct == 2) ? acc02 : acc03;
        const f32x4& a1 = (ct == 0) ? acc10 : (ct == 1) ? acc11 : (ct == 2) ? acc12 : acc13;
        int col = (ch * 4 + ct) * 16 + lr;
        float bv = bias[col];
        #pragma unroll
        for (int i2 = 0; i2 < 4; ++i2) {
            int row0 = rt0 * 16 + lg * 4 + i2;
            __builtin_nontemporal_store(fmaxf(a0[i2] + bv, 0.f),
                                        &out[(size_t)row0 * O_OUT + col]);
        }
        if (has1) {
            #pragma unroll
            for (int i2 = 0; i2 < 4; ++i2) {
                int row1 = rt1 * 16 + lg * 4 + i2;
                __builtin_nontemporal_store(fmaxf(a1[i2] + bv, 0.f),
                                            &out[(size_t)row1 * O_OUT + col]);
            }
        }
    }
}

extern "C" void kernel_launch(void* const* d_in, const int* in_sizes, int n_in,
                              void* d_out, int out_size, void* d_ws, size_t ws_size,
                              hipStream_t stream) {
    (void)in_sizes; (void)n_in; (void)out_size; (void)ws_size;
    const float* x       = (const float*)d_in[0];
    const float* basis_v = (const float*)d_in[1];
    const float* coeffs  = (const float*)d_in[2];
    const float* w_loop  = (const float*)d_in[3];
    const float* bias_p  = (const float*)d_in[4];
    const int*   src     = (const int*)d_in[5];
    const int*   dst     = (const int*)d_in[6];
    const int*   rel     = (const int*)d_in[7];
    float* out = (float*)d_out;

    char* ws = (char*)d_ws;
    unsigned short* Wt2f     = (unsigned short*)(ws);             //     163,840 B
    unsigned short* xb       = (unsigned short*)(ws + 163840);    //  12,800,000 B
    float*          invf     = (float*)(ws + 12963840);           //   1,600,000 B
    int*            begd     = (int*)(ws + 14563840);             //     200,000 B
    int*            cntd     = (int*)(ws + 14763840);             //     200,000 B
    int*            cursor98 = (int*)(ws + 14963840);             //       1,024 B
    unsigned*       coarse   = (unsigned*)(ws + 14964864);        //   3,211,264 B
    unsigned*       epack    = (unsigned*)(ws + 18176128);        //   3,211,264 B
    unsigned short* yfrag    = (unsigned short*)(ws + 21387392);  //  64,000,000 B

    hipMemsetAsync(cursor98, 0, NB1 * sizeof(int), stream);
    prepbin_kernel<<<NB_CONV + NB_WT + NBA, 256, 0, stream>>>(x, xb, basis_v, w_loop, Wt2f,
                                                              src, dst, rel, cursor98, coarse);
    binB_kernel<<<NB1, 512, 0, stream>>>(coarse, cursor98, epack, begd, cntd, invf);
    segagg_kernel<<<N_NODES / 8, 256, 0, stream>>>(xb, begd, cntd, invf, epack, coeffs, yfrag);
    gemm2_kernel<<<(NRG * 2 + 3) / 4, 256, 0, stream>>>(yfrag, Wt2f, bias_p, out);
}

// Round 18
// 101.758 us; speedup vs baseline: 1.5376x; 1.2995x over previous
//
#include <hip/hip_runtime.h>

#define N_NODES 50000
#define E_EDGES 600000
#define D_IN 128
#define O_OUT 128
#define R_REL 8
#define B_BAS 4
#define NB1 98                    // coarse buckets (512 dsts each)
#define NRT 3125                  // 50000 / 16 row tiles (exact)
#define NKC 20                    // 640 / 32 k-chunks
#define BKCAP 8192                // fixed per-bucket capacity (mean 6122, +26 sigma)
#define NRG 1563                  // ceil(50000/32) 32-row groups for gemm2

// prep kernel block ranges
#define NB_CONV 6250              // N*D/1024
#define NB_WT 320                 // 128*640/256

// binning
#define CHUNK_A 2048
#define NBA 293                   // ceil(600000/2048)

typedef __attribute__((ext_vector_type(8))) short bf16x8;
typedef __attribute__((ext_vector_type(4))) short bf16x4;
typedef __attribute__((ext_vector_type(4))) float f32x4;

static __device__ __forceinline__ unsigned short f2bf(float f) {
    unsigned int u = __float_as_uint(f);
    unsigned int r = (u + 0x7fffu + ((u >> 16) & 1u)) >> 16;
    return (unsigned short)r;
}
static __device__ __forceinline__ float bf2f(unsigned short b) {
    return __uint_as_float(((unsigned int)b) << 16);
}

// Fused: x->bf16 convert | Wt2f (fragment-layout weights). Block 0 also zeroes cursor98.
__global__ __launch_bounds__(256) void prep_kernel(const float* __restrict__ x,
                                                   unsigned short* __restrict__ xb,
                                                   const float* __restrict__ basis_v,
                                                   const float* __restrict__ w_loop,
                                                   unsigned short* __restrict__ Wt2f,
                                                   int* __restrict__ cursor98) {
    int b = blockIdx.x;
    if (b == 0 && threadIdx.x < NB1) cursor98[threadIdx.x] = 0;
    if (b < NB_CONV) {
        int i = (b * 256 + threadIdx.x) * 4;
        float4 v = *(const float4*)&x[i];
        ushort4 o;
        o.x = f2bf(v.x); o.y = f2bf(v.y); o.z = f2bf(v.z); o.w = f2bf(v.w);
        *(ushort4*)&xb[i] = o;
    } else {
        int i = (b - NB_CONV) * 256 + threadIdx.x;  // over 8*20*64*8 = 81920
        int j = i & 7, l = (i >> 3) & 63, rest = i >> 9;
        int kc = rest % NKC, ct = rest / NKC;
        int col = ct * 16 + (l & 15);
        int k = kc * 32 + (l >> 4) * 8 + j;
        int r = k >> 7, d = k & 127;
        float v = (r < B_BAS) ? basis_v[((size_t)r * D_IN + d) * O_OUT + col]
                              : w_loop[(size_t)d * O_OUT + col];
        Wt2f[i] = f2bf(v);
    }
}

// Pass A: bin edges into 98 fixed-capacity coarse buckets, block-contiguous runs.
// coarse payload: src(16) | rel(3)<<16 | dlow(9)<<19
__global__ __launch_bounds__(256) void binA_kernel(const int* __restrict__ src,
                                                   const int* __restrict__ dst,
                                                   const int* __restrict__ rel,
                                                   int* __restrict__ cursor98,
                                                   unsigned* __restrict__ coarse) {
    __shared__ int hist[NB1];
    __shared__ int base[NB1];
    int t = threadIdx.x;
    if (t < NB1) hist[t] = 0;
    __syncthreads();
    int e0 = blockIdx.x * CHUNK_A;
    for (int i = t; i < CHUNK_A; i += 256) {
        int e = e0 + i;
        if (e < E_EDGES) atomicAdd(&hist[dst[e] >> 9], 1);
    }
    __syncthreads();
    if (t < NB1) {
        int h = hist[t];
        base[t] = h ? atomicAdd(&cursor98[t], h) : 0;
        hist[t] = 0;
    }
    __syncthreads();
    for (int i = t; i < CHUNK_A; i += 256) {
        int e = e0 + i;
        if (e < E_EDGES) {
            int d = dst[e], b = d >> 9;
            int pos = base[b] + atomicAdd(&hist[b], 1);
            coarse[(size_t)b * BKCAP + pos] = (unsigned)src[e] | ((unsigned)rel[e] << 16)
                                            | ((unsigned)(d & 511) << 19);
        }
    }
}

// Pass B: one block per bucket. LDS (dst,rel) histogram -> invf + per-dst scan
// (begd/cntd) -> exact slot placement.
__global__ __launch_bounds__(512) void binB_kernel(const unsigned* __restrict__ coarse,
                                                   const int* __restrict__ cursor98,
                                                   unsigned* __restrict__ epack,
                                                   int* __restrict__ begd,
                                                   int* __restrict__ cntd,
                                                   float* __restrict__ invf) {
    __shared__ int hist[512 * 8];   // 16 KB: [dlow][rel]
    __shared__ int s[512];
    __shared__ int lcnt[512];
    int b = blockIdx.x, t = threadIdx.x;
    int d0 = b << 9, d = d0 + t;
    #pragma unroll
    for (int r = 0; r < 8; ++r) hist[t * 8 + r] = 0;
    __syncthreads();
    int cnt = cursor98[b];
    const unsigned* cb = coarse + (size_t)b * BKCAP;
    for (int i = t; i < cnt; i += 512) {
        unsigned p = cb[i];
        atomicAdd(&hist[((p >> 19) & 511) * 8 + ((p >> 16) & 7)], 1);
    }
    __syncthreads();
    int c = 0;
    if (d < N_NODES) {
        #pragma unroll
        for (int r = 0; r < 8; ++r) {
            int h = hist[t * 8 + r];
            c += h;
            invf[d * 8 + r] = 1.0f / (float)max(h, 1);
        }
    }
    s[t] = c;
    __syncthreads();
    #pragma unroll
    for (int off = 1; off < 512; off <<= 1) {
        int add = (t >= off) ? s[t - off] : 0;
        __syncthreads();
        s[t] += add;
        __syncthreads();
    }
    int ex = s[t] - c;
    if (d < N_NODES) {
        begd[d] = b * BKCAP + ex;
        cntd[d] = c;
    }
    lcnt[t] = ex;
    __syncthreads();
    for (int i = t; i < cnt; i += 512) {
        unsigned p = cb[i];
        int dlow = (p >> 19) & 511;
        int pos = atomicAdd(&lcnt[dlow], 1);
        epack[(size_t)b * BKCAP + pos] = p & 0x7ffffu;  // src | rel<<16
    }
}

// segagg: 32 lanes per dst node; 4-deep pipelined edge walk (proven depth).
// Writes yfrag in MFMA fragment order:
//   lane l holds k = b*128 + l*4 + m -> kc=b*4+(l>>3), lhi=(l>>1)&3, j=(l&1)*4+m
__global__ __launch_bounds__(256) void segagg_kernel(const unsigned short* __restrict__ xb,
                                                     const int* __restrict__ begd,
                                                     const int* __restrict__ cntd,
                                                     const float* __restrict__ invf,
                                                     const unsigned* __restrict__ epack,
                                                     const float* __restrict__ coeffs,
                                                     unsigned short* __restrict__ yfrag) {
    int d = blockIdx.x * 8 + (threadIdx.x >> 5);  // grid exact: 50000/8
    int l = threadIdx.x & 31;
    int beg = begd[d];
    int n = cntd[d];
    const unsigned* ep = epack + beg;
    float a0[4] = {}, a1[4] = {}, a2[4] = {}, a3[4] = {};
    int k = 0;
    for (; k + 4 <= n; k += 4) {
        unsigned p0 = ep[k], p1 = ep[k + 1], p2 = ep[k + 2], p3 = ep[k + 3];
        int s0 = p0 & 0xffffu, r0 = p0 >> 16;
        int s1 = p1 & 0xffffu, r1 = p1 >> 16;
        int s2 = p2 & 0xffffu, r2 = p2 >> 16;
        int s3 = p3 & 0xffffu, r3 = p3 >> 16;
        bf16x4 v0 = *(const bf16x4*)&xb[(size_t)s0 * D_IN + l * 4];
        bf16x4 v1 = *(const bf16x4*)&xb[(size_t)s1 * D_IN + l * 4];
        bf16x4 v2 = *(const bf16x4*)&xb[(size_t)s2 * D_IN + l * 4];
        bf16x4 v3 = *(const bf16x4*)&xb[(size_t)s3 * D_IN + l * 4];
        float i0 = invf[d * R_REL + r0];
        float i1 = invf[d * R_REL + r1];
        float i2 = invf[d * R_REL + r2];
        float i3 = invf[d * R_REL + r3];
        float4 cA = *(const float4*)&coeffs[r0 * B_BAS];
        float4 cB = *(const float4*)&coeffs[r1 * B_BAS];
        float4 cC = *(const float4*)&coeffs[r2 * B_BAS];
        float4 cD = *(const float4*)&coeffs[r3 * B_BAS];
        cA.x *= i0; cA.y *= i0; cA.z *= i0; cA.w *= i0;
        cB.x *= i1; cB.y *= i1; cB.z *= i1; cB.w *= i1;
        cC.x *= i2; cC.y *= i2; cC.z *= i2; cC.w *= i2;
        cD.x *= i3; cD.y *= i3; cD.z *= i3; cD.w *= i3;
        #pragma unroll
        for (int j = 0; j < 4; ++j) {
            float x0 = bf2f((unsigned short)v0[j]);
            float x1 = bf2f((unsigned short)v1[j]);
            float x2 = bf2f((unsigned short)v2[j]);
            float x3 = bf2f((unsigned short)v3[j]);
            a0[j] += cA.x * x0; a1[j] += cA.y * x0;
            a2[j] += cA.z * x0; a3[j] += cA.w * x0;
            a0[j] += cB.x * x1; a1[j] += cB.y * x1;
            a2[j] += cB.z * x1; a3[j] += cB.w * x1;
            a0[j] += cC.x * x2; a1[j] += cC.y * x2;
            a2[j] += cC.z * x2; a3[j] += cC.w * x2;
            a0[j] += cD.x * x3; a1[j] += cD.y * x3;
            a2[j] += cD.z * x3; a3[j] += cD.w * x3;
        }
    }
    for (; k < n; ++k) {
        unsigned p0 = ep[k];
        int s0 = p0 & 0xffffu, r0 = p0 >> 16;
        bf16x4 v0 = *(const bf16x4*)&xb[(size_t)s0 * D_IN + l * 4];
        float i0 = invf[d * R_REL + r0];
        float4 cA = *(const float4*)&coeffs[r0 * B_BAS];
        cA.x *= i0; cA.y *= i0; cA.z *= i0; cA.w *= i0;
        #pragma unroll
        for (int j = 0; j < 4; ++j) {
            float x0 = bf2f((unsigned short)v0[j]);
            a0[j] += cA.x * x0; a1[j] += cA.y * x0;
            a2[j] += cA.z * x0; a3[j] += cA.w * x0;
        }
    }
    // fragment-layout stores
    int rt = d >> 4, lrow = d & 15;
    int kc0 = l >> 3, lhi = (l >> 1) & 3, jj = (l & 1) * 4;
    size_t rowbase = (size_t)rt * (NKC * 512);   // shorts per rt = 20*64*8
    #pragma unroll
    for (int b = 0; b < 4; ++b) {
        const float* ab = (b == 0) ? a0 : (b == 1) ? a1 : (b == 2) ? a2 : a3;
        ushort4 o;
        o.x = f2bf(ab[0]); o.y = f2bf(ab[1]); o.z = f2bf(ab[2]); o.w = f2bf(ab[3]);
        size_t addr = rowbase + ((size_t)(b * 4 + kc0) * 64 + lhi * 16 + lrow) * 8 + jj;
        *(ushort4*)&yfrag[addr] = o;
    }
    ushort4 xv = *(const ushort4*)&xb[(size_t)d * D_IN + l * 4];
    size_t addr = rowbase + ((size_t)(16 + kc0) * 64 + lhi * 16 + lrow) * 8 + jj;
    *(ushort4*)&yfrag[addr] = xv;
}

// gemm2: out = relu(A @ Wstack + bias), fragment-layout operands.
// Each wave: 32 rows (2 A-frags) x 64 cols (4 ct) -> 3126 waves.
// Regular loads/stores throughout (NT variants regressed, rounds 16-17).
__global__ __launch_bounds__(256) void gemm2_kernel(const unsigned short* __restrict__ yfrag,
                                                    const unsigned short* __restrict__ Wt2f,
                                                    const float* __restrict__ bias,
                                                    float* __restrict__ out) {
    const int w = threadIdx.x >> 6, l = threadIdx.x & 63;
    const int wid = blockIdx.x * 4 + w;
    if (wid >= NRG * 2) return;
    const int g = wid >> 1;
    const int ch = wid & 1;                    // col half: ct base 0 or 4
    const int rt0 = g * 2;
    const int rt1 = (rt0 + 1 < NRT) ? rt0 + 1 : rt0;   // clamp (last group)
    const bool has1 = (rt0 + 1 < NRT);
    const unsigned short* ya0 = yfrag + (size_t)rt0 * (NKC * 512) + l * 8;
    const unsigned short* ya1 = yfrag + (size_t)rt1 * (NKC * 512) + l * 8;
    const unsigned short* wb = Wt2f + (size_t)(ch * 4) * (NKC * 512) + l * 8;
    const int KSTEP = 512;

    f32x4 acc00 = {}, acc01 = {}, acc02 = {}, acc03 = {};
    f32x4 acc10 = {}, acc11 = {}, acc12 = {}, acc13 = {};

#define LA0(kc) (*(const bf16x8*)&ya0[(kc) * KSTEP])
#define LA1(kc) (*(const bf16x8*)&ya1[(kc) * KSTEP])
#define LB(ct, kc) (*(const bf16x8*)&wb[((ct) * NKC + (kc)) * KSTEP])

    bf16x8 aE0 = LA0(0), aE1 = LA1(0);
    bf16x8 bE0 = LB(0, 0), bE1 = LB(1, 0), bE2 = LB(2, 0), bE3 = LB(3, 0);
    bf16x8 aO0 = LA0(1), aO1 = LA1(1);
    bf16x8 bO0 = LB(0, 1), bO1 = LB(1, 1), bO2 = LB(2, 1), bO3 = LB(3, 1);

    #pragma unroll
    for (int kc = 0; kc < NKC; kc += 2) {
        acc00 = __builtin_amdgcn_mfma_f32_16x16x32_bf16(aE0, bE0, acc00, 0, 0, 0);
        acc01 = __builtin_amdgcn_mfma_f32_16x16x32_bf16(aE0, bE1, acc01, 0, 0, 0);
        acc02 = __builtin_amdgcn_mfma_f32_16x16x32_bf16(aE0, bE2, acc02, 0, 0, 0);
        acc03 = __builtin_amdgcn_mfma_f32_16x16x32_bf16(aE0, bE3, acc03, 0, 0, 0);
        acc10 = __builtin_amdgcn_mfma_f32_16x16x32_bf16(aE1, bE0, acc10, 0, 0, 0);
        acc11 = __builtin_amdgcn_mfma_f32_16x16x32_bf16(aE1, bE1, acc11, 0, 0, 0);
        acc12 = __builtin_amdgcn_mfma_f32_16x16x32_bf16(aE1, bE2, acc12, 0, 0, 0);
        acc13 = __builtin_amdgcn_mfma_f32_16x16x32_bf16(aE1, bE3, acc13, 0, 0, 0);
        if (kc + 2 < NKC) {
            aE0 = LA0(kc + 2); aE1 = LA1(kc + 2);
            bE0 = LB(0, kc + 2); bE1 = LB(1, kc + 2);
            bE2 = LB(2, kc + 2); bE3 = LB(3, kc + 2);
        }
        acc00 = __builtin_amdgcn_mfma_f32_16x16x32_bf16(aO0, bO0, acc00, 0, 0, 0);
        acc01 = __builtin_amdgcn_mfma_f32_16x16x32_bf16(aO0, bO1, acc01, 0, 0, 0);
        acc02 = __builtin_amdgcn_mfma_f32_16x16x32_bf16(aO0, bO2, acc02, 0, 0, 0);
        acc03 = __builtin_amdgcn_mfma_f32_16x16x32_bf16(aO0, bO3, acc03, 0, 0, 0);
        acc10 = __builtin_amdgcn_mfma_f32_16x16x32_bf16(aO1, bO0, acc10, 0, 0, 0);
        acc11 = __builtin_amdgcn_mfma_f32_16x16x32_bf16(aO1, bO1, acc11, 0, 0, 0);
        acc12 = __builtin_amdgcn_mfma_f32_16x16x32_bf16(aO1, bO2, acc12, 0, 0, 0);
        acc13 = __builtin_amdgcn_mfma_f32_16x16x32_bf16(aO1, bO3, acc13, 0, 0, 0);
        if (kc + 3 < NKC) {
            aO0 = LA0(kc + 3); aO1 = LA1(kc + 3);
            bO0 = LB(0, kc + 3); bO1 = LB(1, kc + 3);
            bO2 = LB(2, kc + 3); bO3 = LB(3, kc + 3);
        }
    }
#undef LA0
#undef LA1
#undef LB

    // epilogue: C/D layout col=lane&15, row=(lane>>4)*4+i  [m89-verified]
    const int lr = l & 15, lg = l >> 4;
    #pragma unroll
    for (int ct = 0; ct < 4; ++ct) {
        const f32x4& a0 = (ct == 0) ? acc00 : (ct == 1) ? acc01 : (ct == 2) ? acc02 : acc03;
        const f32x4& a1 = (ct == 0) ? acc10 : (ct == 1) ? acc11 : (ct == 2) ? acc12 : acc13;
        int col = (ch * 4 + ct) * 16 + lr;
        float bv = bias[col];
        #pragma unroll
        for (int i2 = 0; i2 < 4; ++i2) {
            int row0 = rt0 * 16 + lg * 4 + i2;
            out[(size_t)row0 * O_OUT + col] = fmaxf(a0[i2] + bv, 0.f);
        }
        if (has1) {
            #pragma unroll
            for (int i2 = 0; i2 < 4; ++i2) {
                int row1 = rt1 * 16 + lg * 4 + i2;
                out[(size_t)row1 * O_OUT + col] = fmaxf(a1[i2] + bv, 0.f);
            }
        }
    }
}

extern "C" void kernel_launch(void* const* d_in, const int* in_sizes, int n_in,
                              void* d_out, int out_size, void* d_ws, size_t ws_size,
                              hipStream_t stream) {
    (void)in_sizes; (void)n_in; (void)out_size; (void)ws_size;
    const float* x       = (const float*)d_in[0];
    const float* basis_v = (const float*)d_in[1];
    const float* coeffs  = (const float*)d_in[2];
    const float* w_loop  = (const float*)d_in[3];
    const float* bias_p  = (const float*)d_in[4];
    const int*   src     = (const int*)d_in[5];
    const int*   dst     = (const int*)d_in[6];
    const int*   rel     = (const int*)d_in[7];
    float* out = (float*)d_out;

    char* ws = (char*)d_ws;
    unsigned short* Wt2f     = (unsigned short*)(ws);             //     163,840 B
    unsigned short* xb       = (unsigned short*)(ws + 163840);    //  12,800,000 B
    float*          invf     = (float*)(ws + 12963840);           //   1,600,000 B
    int*            begd     = (int*)(ws + 14563840);             //     200,000 B
    int*            cntd     = (int*)(ws + 14763840);             //     200,000 B
    int*            cursor98 = (int*)(ws + 14963840);             //       1,024 B
    unsigned*       coarse   = (unsigned*)(ws + 14964864);        //   3,211,264 B
    unsigned*       epack    = (unsigned*)(ws + 18176128);        //   3,211,264 B
    unsigned short* yfrag    = (unsigned short*)(ws + 21387392);  //  64,000,000 B

    prep_kernel<<<NB_CONV + NB_WT, 256, 0, stream>>>(x, xb, basis_v, w_loop, Wt2f, cursor98);
    binA_kernel<<<NBA, 256, 0, stream>>>(src, dst, rel, cursor98, coarse);
    binB_kernel<<<NB1, 512, 0, stream>>>(coarse, cursor98, epack, begd, cntd, invf);
    segagg_kernel<<<N_NODES / 8, 256, 0, stream>>>(xb, begd, cntd, invf, epack, coeffs, yfrag);
    gemm2_kernel<<<(NRG * 2 + 3) / 4, 256, 0, stream>>>(yfrag, Wt2f, bias_p, out);
}